// Round 4
// baseline (7255.904 us; speedup 1.0000x reference)
//
#include <hip/hip_runtime.h>
#include <math.h>

// ============================================================================
// Persistent per-signal FFT ISTA solver, radix-8, register-resident edition.
//
// Math (identical to the r1/r2/r3 verified versions):
//   u_{t+1} = u_t - 0.05*(I-P)*clamp20(u_t),  u_0 = 100*DCT(scatter(x[idxs]))
//   P*h = DCT2(mask(IDCT(h))) via FFT+ (DIF) then FFT- (DIT).
//   out = 0.01*IDCT(u_99 - 0.05*clamp20(u_99)).
//
// FFT decomposition: 2048 = 8*8*8*4, 256 threads/signal, 8 cf pts/thread.
//   Slot p = 256b' + 32c' + 4d' + e' holds Y[m], m = b' + 8c' + 64d' + 512e'.
//   LDS XOR-swizzle swz(p) = p ^ (((p>>5)&7)<<2): S0/T3, S1/T2, S2/T1 all hit
//   the 4-dword/bank minimum; S3/T0 float4 quad is 2-way (free).
//   S3 + measurement mask + T0 fuse in registers (8-bit mask/thread).
//
// r3 -> r4: __launch_bounds__(256,4) replaced by amdgpu_waves_per_eu(4,4).
// r2/r3 both spilled ~1.1 KB/thread of loop-invariant twiddles (VGPR=64,
// WRITE 286 MB = scratch written once, FETCH 23.6 GB = re-read 99x, scratch
// footprint 268 MB > L3): LLVM's perf-hint pushed the allocator to the
// 8-waves/EU (64-reg) bucket. Pinning waves-per-eu to exactly 4 gives the
// 128-reg budget the ~110-reg live set needs. Dead double-init removed.
// ============================================================================

#define PIF 3.14159265358979323846f
#define C0F 0.022097086912079608f      // sqrt(1/2048)
#define TWOC0 0.044194173824159216f    // 2*sqrt(1/2048)
#define CNF 0.03125f                   // sqrt(2/2048)
#define SPW 3                          // signals per block; grid = 3072/3 = 1024

typedef float2 cf;

__device__ __forceinline__ int load_idx(const int* p, int j) {
    return (p[1] == 0) ? p[2 * j] : p[j];   // int64 (lo,0) pairs or int32
}
__device__ __forceinline__ int pinv(int m) {   // frequency -> slot
    return ((m & 7) << 8) | (((m >> 3) & 7) << 5) | (((m >> 6) & 7) << 2) | ((m >> 9) & 3);
}
__device__ __forceinline__ int permf(int p) {  // slot -> frequency
    return (p >> 8) | (((p >> 5) & 7) << 3) | (((p >> 2) & 7) << 6) | ((p & 3) << 9);
}
__device__ __forceinline__ float clamp20(float g) {
    return fminf(fmaxf(20.f * g, -1.f), 1.f);
}
__device__ __forceinline__ cf cadd(cf a, cf b) { return make_float2(a.x + b.x, a.y + b.y); }
__device__ __forceinline__ cf csub(cf a, cf b) { return make_float2(a.x - b.x, a.y - b.y); }
__device__ __forceinline__ cf cmul(cf a, cf b) {
    return make_float2(a.x * b.x - a.y * b.y, a.x * b.y + a.y * b.x);
}
__device__ __forceinline__ cf cmulc(cf a, cf b) {   // a * conj(b)
    return make_float2(a.x * b.x + a.y * b.y, a.y * b.x - a.x * b.y);
}
template <int S> __device__ __forceinline__ cf imul(cf z) {  // (S*i)*z
    return (S > 0) ? make_float2(-z.y, z.x) : make_float2(z.y, -z.x);
}

// DFT-8 over named refs: v_j = sum_b v_in_b * w8^{S*b*j}
template <int S>
__device__ __forceinline__ void dft8r(cf& v0, cf& v1, cf& v2, cf& v3,
                                      cf& v4, cf& v5, cf& v6, cf& v7) {
    const float R2 = 0.70710678118654752f;
    cf A0 = cadd(v0, v4), D0 = csub(v0, v4);
    cf A1 = cadd(v1, v5), D1 = csub(v1, v5);
    cf A2 = cadd(v2, v6), D2 = csub(v2, v6);
    cf A3 = cadd(v3, v7), D3 = csub(v3, v7);
    const cf w8  = make_float2(R2, (S > 0) ? R2 : -R2);
    const cf w83 = make_float2(-R2, (S > 0) ? R2 : -R2);
    D1 = cmul(D1, w8);
    D2 = imul<S>(D2);
    D3 = cmul(D3, w83);
    cf E0 = cadd(A0, A2), E1 = csub(A0, A2);
    cf O0 = cadd(A1, A3), O1 = imul<S>(csub(A1, A3));
    cf F0 = cadd(D0, D2), F1 = csub(D0, D2);
    cf P0 = cadd(D1, D3), P1 = imul<S>(csub(D1, D3));
    v0 = cadd(E0, O0); v2 = cadd(E1, O1);
    v4 = csub(E0, O0); v6 = csub(E1, O1);
    v1 = cadd(F0, P0); v3 = cadd(F1, P1);
    v5 = csub(F0, P0); v7 = csub(F1, P1);
}

template <int S>
__device__ __forceinline__ void dft4r(cf& v0, cf& v1, cf& v2, cf& v3) {
    cf E0 = cadd(v0, v2), E1 = csub(v0, v2);
    cf O0 = cadd(v1, v3), O1 = imul<S>(csub(v1, v3));
    v0 = cadd(E0, O0); v1 = cadd(E1, O1);
    v2 = csub(E0, O0); v3 = csub(E1, O1);
}

// cos/sin(pi*b/16) literals, b = 0..7
#define CRL0 1.0f
#define CRL1 0.980785280403230449f
#define CRL2 0.923879532511286756f
#define CRL3 0.831469612302545237f
#define CRL4 0.707106781186547524f
#define CRL5 0.555570233019602225f
#define CRL6 0.382683432365089772f
#define CRL7 0.195090322016128268f
#define SRL0 0.0f
#define SRL1 CRL7
#define SRL2 CRL6
#define SRL3 CRL5
#define SRL4 CRL4
#define SRL5 CRL3
#define SRL6 CRL2
#define SRL7 CRL1

#define SWZ(p) ((p) ^ ((((p) >> 5) & 7) << 2))
#define A0j(j) (tsw + 256 * (j))
#define A1j(j) ((s1b ^ ((j) << 2)) + 32 * (j) + 256 * t5)
#define A2j(j) (s2k + 4 * ((j) ^ s2c) + 32 * s2c + 256 * t5)

#define LOAD8(A) cf v0 = wk[A(0)], v1 = wk[A(1)], v2 = wk[A(2)], v3 = wk[A(3)], \
                    v4 = wk[A(4)], v5 = wk[A(5)], v6 = wk[A(6)], v7 = wk[A(7)]
#define STORE8(A) wk[A(0)] = v0; wk[A(1)] = v1; wk[A(2)] = v2; wk[A(3)] = v3; \
                  wk[A(4)] = v4; wk[A(5)] = v5; wk[A(6)] = v6; wk[A(7)] = v7
#define TWF(P) v1 = cmul(v1, P##1); v2 = cmul(v2, P##2); v3 = cmul(v3, P##3); \
               v4 = cmul(v4, P##4); v5 = cmul(v5, P##5); v6 = cmul(v6, P##6); \
               v7 = cmul(v7, P##7)
#define TWB(P) v1 = cmulc(v1, P##1); v2 = cmulc(v2, P##2); v3 = cmulc(v3, P##3); \
               v4 = cmulc(v4, P##4); v5 = cmulc(v5, P##5); v6 = cmulc(v6, P##6); \
               v7 = cmulc(v7, P##7)

#define DIFMID(A, P) { LOAD8(A); dft8r<1>(v0, v1, v2, v3, v4, v5, v6, v7); \
                       TWF(P); STORE8(A); }
#define DITMID(A, P) { LOAD8(A); TWB(P); dft8r<-1>(v0, v1, v2, v3, v4, v5, v6, v7); \
                       STORE8(A); }

// V-build for DIF head (fin selects iteration vs final nonlinearity)
#define MKVB(b, vo) { \
    const int k_ = t + 256 * (b); \
    const int kN_ = (2048 - k_) & 2047; \
    const float gk_ = g[k_], gN_ = g[kN_]; \
    float hk_, hN_; \
    if (fin) { hk_ = gk_ - 0.05f * clamp20(gk_); hN_ = gN_ - 0.05f * clamp20(gN_); } \
    else     { hk_ = clamp20(gk_);               hN_ = clamp20(gN_); } \
    const bool kz_ = ((b) == 0) && (t == 0); \
    const float Xk_ = (kz_ ? TWOC0 : CNF) * hk_; \
    const float XN_ = kz_ ? 0.f : CNF * hN_; \
    const float cc_ = c0a * (CRL##b) - s0a * (SRL##b); \
    const float ss_ = s0a * (CRL##b) + c0a * (SRL##b); \
    vo = make_float2(0.5f * (Xk_ * cc_ + XN_ * ss_), 0.5f * (Xk_ * ss_ - XN_ * cc_)); }

#define HEADS0(finv) { \
    const bool fin = (finv); \
    cf v0, v1, v2, v3, v4, v5, v6, v7; \
    MKVB(0, v0) MKVB(1, v1) MKVB(2, v2) MKVB(3, v3) \
    MKVB(4, v4) MKVB(5, v5) MKVB(6, v6) MKVB(7, v7) \
    dft8r<1>(v0, v1, v2, v3, v4, v5, v6, v7); \
    TWF(W); STORE8(A0j); }

#define TAILJ(j) { \
    const int k_ = t + 256 * (j); \
    const float cc_ = c0a * (CRL##j) - s0a * (SRL##j); \
    const float ss_ = s0a * (CRL##j) + c0a * (SRL##j); \
    const float Cv_ = v##j.x * cc_ + v##j.y * ss_; \
    const float u_ = ((((j) == 0) && (t == 0)) ? C0F : CNF) * Cv_; \
    if (init) g[k_] = u_; \
    else { const float gk_ = g[k_]; g[k_] = gk_ + 0.05f * (u_ - clamp20(gk_)); } }

#define TAILT3(initv) { \
    const bool init = (initv); \
    LOAD8(A0j); TWB(W); dft8r<-1>(v0, v1, v2, v3, v4, v5, v6, v7); \
    TAILJ(0) TAILJ(1) TAILJ(2) TAILJ(3) TAILJ(4) TAILJ(5) TAILJ(6) TAILJ(7) }

// S3 + mask + T0, all in registers (one 16-pt quad, q = 0 or 1)
#define QUADMASK(q) { \
    const int pb_ = 8 * t + 4 * (q); \
    const int a_ = SWZ(pb_); \
    float4 lo_ = *(const float4*)(&wk[a_]); \
    float4 hi_ = *(const float4*)(&wk[a_ + 2]); \
    cf u0 = make_float2(lo_.x, lo_.y), u1 = make_float2(lo_.z, lo_.w); \
    cf u2 = make_float2(hi_.x, hi_.y), u3 = make_float2(hi_.z, hi_.w); \
    dft4r<1>(u0, u1, u2, u3); \
    u0 = make_float2(u0.x * (float)((msk >> (4 * (q) + 0)) & 1u), 0.f); \
    u1 = make_float2(u1.x * (float)((msk >> (4 * (q) + 1)) & 1u), 0.f); \
    u2 = make_float2(u2.x * (float)((msk >> (4 * (q) + 2)) & 1u), 0.f); \
    u3 = make_float2(u3.x * (float)((msk >> (4 * (q) + 3)) & 1u), 0.f); \
    dft4r<-1>(u0, u1, u2, u3); \
    *(float4*)(&wk[a_])     = make_float4(u0.x, u0.y, u1.x, u1.y); \
    *(float4*)(&wk[a_ + 2]) = make_float4(u2.x, u2.y, u3.x, u3.y); }

// Plain T0 quad (init path: input already masked & real)
#define QUADT0(q) { \
    const int pb_ = 8 * t + 4 * (q); \
    const int a_ = SWZ(pb_); \
    float4 lo_ = *(const float4*)(&wk[a_]); \
    float4 hi_ = *(const float4*)(&wk[a_ + 2]); \
    cf u0 = make_float2(lo_.x, lo_.y), u1 = make_float2(lo_.z, lo_.w); \
    cf u2 = make_float2(hi_.x, hi_.y), u3 = make_float2(hi_.z, hi_.w); \
    dft4r<-1>(u0, u1, u2, u3); \
    *(float4*)(&wk[a_])     = make_float4(u0.x, u0.y, u1.x, u1.y); \
    *(float4*)(&wk[a_ + 2]) = make_float4(u2.x, u2.y, u3.x, u3.y); }

__global__ void __attribute__((amdgpu_flat_work_group_size(256, 256)))
__attribute__((amdgpu_waves_per_eu(4, 4))) ista_fft_kernel(
    const float* __restrict__ x, const int* __restrict__ idxs,
    float* __restrict__ out)
{
    __shared__ __align__(16) cf wk[2048];   // 16 KB, swizzled slot space
    __shared__ float g[2048];               // 8 KB
    __shared__ unsigned mbm[64];

    const int t = threadIdx.x;
    const int t5 = t >> 5;
    const int s1b = t & 31;
    const int s2k = t & 3, s2c = (t >> 2) & 7;
    const int tsw = SWZ(t);

    if (t < 64) mbm[t] = 0u;
    __syncthreads();

    const int mi0 = load_idx(idxs, t), mi1 = load_idx(idxs, t + 256);
    const int yd0 = (mi0 & 1) ? (2047 - (mi0 >> 1)) : (mi0 >> 1);
    const int yd1 = (mi1 & 1) ? (2047 - (mi1 >> 1)) : (mi1 >> 1);
    const int pm0 = pinv(yd0), pm1 = pinv(yd1);
    atomicOr(&mbm[pm0 >> 5], 1u << (pm0 & 31));
    atomicOr(&mbm[pm1 >> 5], 1u << (pm1 & 31));
    const int sl0 = SWZ(pm0), sl1 = SWZ(pm1);
    __syncthreads();
    const unsigned msk = (mbm[t >> 2] >> ((t & 3) * 8)) & 0xffu;

    // thread-invariant twiddles, all in named registers
    float s0a, c0a; sincosf(PIF * (float)t * (1.f / 4096.f), &s0a, &c0a);
    float sww, cww; sincosf(2.f * PIF * (float)t   * (1.f / 2048.f), &sww, &cww);
    float soo, coo; sincosf(2.f * PIF * (float)s1b * (1.f / 256.f),  &soo, &coo);
    float sll, cll; sincosf(2.f * PIF * (float)s2k * (1.f / 32.f),   &sll, &cll);
    const cf W1 = make_float2(cww, sww);
    const cf W2 = cmul(W1, W1), W3 = cmul(W2, W1), W4 = cmul(W2, W2),
             W5 = cmul(W3, W2), W6 = cmul(W3, W3), W7 = cmul(W4, W3);
    const cf O1 = make_float2(coo, soo);
    const cf O2 = cmul(O1, O1), O3 = cmul(O2, O1), O4 = cmul(O2, O2),
             O5 = cmul(O3, O2), O6 = cmul(O3, O3), O7 = cmul(O4, O3);
    const cf L1 = make_float2(cll, sll);
    const cf L2 = cmul(L1, L1), L3 = cmul(L2, L1), L4 = cmul(L2, L2),
             L5 = cmul(L3, L2), L6 = cmul(L3, L3), L7 = cmul(L4, L3);

#pragma unroll 1
    for (int s = 0; s < SPW; ++s) {
        const int r = blockIdx.x * SPW + s;

        // ---- init: wk = scatter(100*x[r, idxs]) in swizzled slot space ----
#pragma unroll
        for (int j = 0; j < 8; ++j) wk[t + 256 * j] = make_float2(0.f, 0.f);
        __syncthreads();
        wk[sl0] = make_float2(100.f * x[(size_t)r * 2048 + mi0], 0.f);
        wk[sl1] = make_float2(100.f * x[(size_t)r * 2048 + mi1], 0.f);
        __syncthreads();
        QUADT0(0) QUADT0(1)                // plain T0
        __syncthreads();
        DITMID(A2j, L); __syncthreads();   // T1
        DITMID(A1j, O); __syncthreads();   // T2
        TAILT3(true);   __syncthreads();   // g = u0

        // ---- 99 iterations ----
#pragma unroll 1
        for (int it = 0; it < 99; ++it) {
            HEADS0(false);  __syncthreads();   // S0 (reads g)
            DIFMID(A1j, O); __syncthreads();   // S1
            DIFMID(A2j, L); __syncthreads();   // S2
            QUADMASK(0) QUADMASK(1)            // S3 + mask + T0 in regs
            __syncthreads();
            DITMID(A2j, L); __syncthreads();   // T1
            DITMID(A1j, O); __syncthreads();   // T2
            TAILT3(false);  __syncthreads();   // g update
        }

        // ---- final: out = 0.01 * IDCT(F') ----
        HEADS0(true);   __syncthreads();
        DIFMID(A1j, O); __syncthreads();
        DIFMID(A2j, L); __syncthreads();
#pragma unroll
        for (int q = 0; q < 2; ++q) {          // S3 + reorder to x-order via g
            const int pb_ = 8 * t + 4 * q;
            const int a_ = SWZ(pb_);
            float4 lo_ = *(const float4*)(&wk[a_]);
            float4 hi_ = *(const float4*)(&wk[a_ + 2]);
            cf u0 = make_float2(lo_.x, lo_.y), u1 = make_float2(lo_.z, lo_.w);
            cf u2 = make_float2(hi_.x, hi_.y), u3 = make_float2(hi_.z, hi_.w);
            dft4r<1>(u0, u1, u2, u3);
            {
                const int m = permf(pb_ + 0);
                g[(m < 1024) ? (m << 1) : (4095 - (m << 1))] = 0.01f * u0.x;
            }
            {
                const int m = permf(pb_ + 1);
                g[(m < 1024) ? (m << 1) : (4095 - (m << 1))] = 0.01f * u1.x;
            }
            {
                const int m = permf(pb_ + 2);
                g[(m < 1024) ? (m << 1) : (4095 - (m << 1))] = 0.01f * u2.x;
            }
            {
                const int m = permf(pb_ + 3);
                g[(m < 1024) ? (m << 1) : (4095 - (m << 1))] = 0.01f * u3.x;
            }
        }
        __syncthreads();
#pragma unroll
        for (int j = 0; j < 8; ++j)
            out[(size_t)r * 2048 + t + 256 * j] = g[t + 256 * j];
    }
}

extern "C" void kernel_launch(void* const* d_in, const int* in_sizes, int n_in,
                              void* d_out, int out_size, void* d_ws, size_t ws_size,
                              hipStream_t stream) {
    (void)in_sizes; (void)n_in; (void)out_size; (void)d_ws; (void)ws_size;
    const float* x = (const float*)d_in[0];
    const int* idxs = (const int*)d_in[1];
    ista_fft_kernel<<<dim3(3072 / SPW), dim3(256), 0, stream>>>(x, idxs, (float*)d_out);
}

// Round 6
// 2563.772 us; speedup vs baseline: 2.8302x; 2.8302x over previous
//
#include <hip/hip_runtime.h>
#include <math.h>

// ============================================================================
// Persistent per-signal FFT ISTA solver, radix-8, spill-proof edition.
// (r6 = r5 resubmission; r5 bench was an infra failure — container acquire —
//  with no compile/correctness verdict. Kernel unchanged.)
//
// Math (identical to r1..r4, all PASSED):
//   u_{t+1} = u_t - 0.05*(I-P)*clamp20(u_t),  u_0 = 100*DCT(scatter(x[idxs]))
//   P*h = DCT2(mask(IDCT(h))) via FFT+ (DIF) then FFT- (DIT).
//   out = 0.01*IDCT(u_99 - 0.05*clamp20(u_99)).
//
// FFT: 2048 = 8*8*8*4, 256 threads/signal, 8 cf/thread.
//   Slot p = 256b' + 32c' + 4d' + e' holds Y[m], m = b' + 8c' + 64d' + 512e'.
//   LDS XOR-swizzle swz(p) = p ^ (((p>>5)&7)<<2): stage accesses at the
//   4-dword/bank minimum; S3/T0 float4 quad 2-way (free).
//
// The spill fix: r2/r3/r4 all spilled ~0.9KB/thread of LICM-hoisted
// loop-invariants (VGPR pinned at 64; FETCH 23 GB = scratch re-read 99x,
// WRITE 266 MB = written once; FETCH/WRITE ratio 88 ~= iteration count).
// Now the only loop-carried invariants are 15 scalars (W1/O1/L1 generators,
// c0a/s0a, 6 addr ints, msk), re-anchored each iteration with an empty asm
// so NOTHING derived from them can be hoisted; twiddle powers are rebuilt
// per stage by chained cmul (+~20% VALU at 19% VALUBusy = free). Peak live
// ~46 regs -> fits the 64-reg bucket with zero scratch. SPW=2 (grid 1536 =
// 6 resident blocks/CU at 24.8 KB LDS).
// ============================================================================

#define PIF 3.14159265358979323846f
#define C0F 0.022097086912079608f      // sqrt(1/2048)
#define TWOC0 0.044194173824159216f    // 2*sqrt(1/2048)
#define CNF 0.03125f                   // sqrt(2/2048)
#define SPW 2                          // signals per block; grid = 3072/2 = 1536

typedef float2 cf;

__device__ __forceinline__ int load_idx(const int* p, int j) {
    return (p[1] == 0) ? p[2 * j] : p[j];   // int64 (lo,0) pairs or int32
}
__device__ __forceinline__ int pinv(int m) {   // frequency -> slot
    return ((m & 7) << 8) | (((m >> 3) & 7) << 5) | (((m >> 6) & 7) << 2) | ((m >> 9) & 3);
}
__device__ __forceinline__ int permf(int p) {  // slot -> frequency
    return (p >> 8) | (((p >> 5) & 7) << 3) | (((p >> 2) & 7) << 6) | ((p & 3) << 9);
}
__device__ __forceinline__ float clamp20(float g) {
    return fminf(fmaxf(20.f * g, -1.f), 1.f);
}
__device__ __forceinline__ cf cadd(cf a, cf b) { return make_float2(a.x + b.x, a.y + b.y); }
__device__ __forceinline__ cf csub(cf a, cf b) { return make_float2(a.x - b.x, a.y - b.y); }
__device__ __forceinline__ cf cmul(cf a, cf b) {
    return make_float2(a.x * b.x - a.y * b.y, a.x * b.y + a.y * b.x);
}
__device__ __forceinline__ cf cmulc(cf a, cf b) {   // a * conj(b)
    return make_float2(a.x * b.x + a.y * b.y, a.y * b.x - a.x * b.y);
}
template <int S> __device__ __forceinline__ cf imul(cf z) {  // (S*i)*z
    return (S > 0) ? make_float2(-z.y, z.x) : make_float2(z.y, -z.x);
}

// DFT-8 over named refs: v_j = sum_b v_in_b * w8^{S*b*j}
template <int S>
__device__ __forceinline__ void dft8r(cf& v0, cf& v1, cf& v2, cf& v3,
                                      cf& v4, cf& v5, cf& v6, cf& v7) {
    const float R2 = 0.70710678118654752f;
    cf A0 = cadd(v0, v4), D0 = csub(v0, v4);
    cf A1 = cadd(v1, v5), D1 = csub(v1, v5);
    cf A2 = cadd(v2, v6), D2 = csub(v2, v6);
    cf A3 = cadd(v3, v7), D3 = csub(v3, v7);
    const cf w8  = make_float2(R2, (S > 0) ? R2 : -R2);
    const cf w83 = make_float2(-R2, (S > 0) ? R2 : -R2);
    D1 = cmul(D1, w8);
    D2 = imul<S>(D2);
    D3 = cmul(D3, w83);
    cf E0 = cadd(A0, A2), E1 = csub(A0, A2);
    cf O0 = cadd(A1, A3), O1 = imul<S>(csub(A1, A3));
    cf F0 = cadd(D0, D2), F1 = csub(D0, D2);
    cf P0 = cadd(D1, D3), P1 = imul<S>(csub(D1, D3));
    v0 = cadd(E0, O0); v2 = cadd(E1, O1);
    v4 = csub(E0, O0); v6 = csub(E1, O1);
    v1 = cadd(F0, P0); v3 = cadd(F1, P1);
    v5 = csub(F0, P0); v7 = csub(F1, P1);
}

template <int S>
__device__ __forceinline__ void dft4r(cf& v0, cf& v1, cf& v2, cf& v3) {
    cf E0 = cadd(v0, v2), E1 = csub(v0, v2);
    cf O0 = cadd(v1, v3), O1 = imul<S>(csub(v1, v3));
    v0 = cadd(E0, O0); v1 = cadd(E1, O1);
    v2 = csub(E0, O0); v3 = csub(E1, O1);
}

// cos/sin(pi*b/16) literals, b = 0..7
#define CRL0 1.0f
#define CRL1 0.980785280403230449f
#define CRL2 0.923879532511286756f
#define CRL3 0.831469612302545237f
#define CRL4 0.707106781186547524f
#define CRL5 0.555570233019602225f
#define CRL6 0.382683432365089772f
#define CRL7 0.195090322016128268f
#define SRL0 0.0f
#define SRL1 CRL7
#define SRL2 CRL6
#define SRL3 CRL5
#define SRL4 CRL4
#define SRL5 CRL3
#define SRL6 CRL2
#define SRL7 CRL1

#define SWZ(p) ((p) ^ ((((p) >> 5) & 7) << 2))
#define A0j(j) (tswv + 256 * (j))
#define A1j(j) ((s1bv ^ ((j) << 2)) + 32 * (j) + 256 * t5v)
#define A2j(j) (s2kv + 4 * ((j) ^ s2cv) + 32 * s2cv + 256 * t5v)

#define LOAD8(A) cf v0 = wk[A(0)], v1 = wk[A(1)], v2 = wk[A(2)], v3 = wk[A(3)], \
                    v4 = wk[A(4)], v5 = wk[A(5)], v6 = wk[A(6)], v7 = wk[A(7)]
#define STORE8(A) wk[A(0)] = v0; wk[A(1)] = v1; wk[A(2)] = v2; wk[A(3)] = v3; \
                  wk[A(4)] = v4; wk[A(5)] = v5; wk[A(6)] = v6; wk[A(7)] = v7

// chained twiddle powers from the generator (PX,PY): w walks P^1..P^7
#define TWCHAINF(PX, PY) { const cf P_ = make_float2((PX), (PY)); cf w_ = P_; \
    v1 = cmul(v1, w_); w_ = cmul(w_, P_); v2 = cmul(v2, w_); w_ = cmul(w_, P_); \
    v3 = cmul(v3, w_); w_ = cmul(w_, P_); v4 = cmul(v4, w_); w_ = cmul(w_, P_); \
    v5 = cmul(v5, w_); w_ = cmul(w_, P_); v6 = cmul(v6, w_); w_ = cmul(w_, P_); \
    v7 = cmul(v7, w_); }
#define TWCHAINB(PX, PY) { const cf P_ = make_float2((PX), (PY)); cf w_ = P_; \
    v1 = cmulc(v1, w_); w_ = cmul(w_, P_); v2 = cmulc(v2, w_); w_ = cmul(w_, P_); \
    v3 = cmulc(v3, w_); w_ = cmul(w_, P_); v4 = cmulc(v4, w_); w_ = cmul(w_, P_); \
    v5 = cmulc(v5, w_); w_ = cmul(w_, P_); v6 = cmulc(v6, w_); w_ = cmul(w_, P_); \
    v7 = cmulc(v7, w_); }

#define DIFMID(A, PX, PY) { LOAD8(A); dft8r<1>(v0, v1, v2, v3, v4, v5, v6, v7); \
                            TWCHAINF(PX, PY); STORE8(A); }
#define DITMID(A, PX, PY) { LOAD8(A); TWCHAINB(PX, PY); \
                            dft8r<-1>(v0, v1, v2, v3, v4, v5, v6, v7); STORE8(A); }

// V-build for DIF head (fin selects iteration vs final nonlinearity)
#define MKVB(b, vo) { \
    const int k_ = ta + 256 * (b); \
    const int kN_ = (2048 - k_) & 2047; \
    const float gk_ = g[k_], gN_ = g[kN_]; \
    float hk_, hN_; \
    if (fin) { hk_ = gk_ - 0.05f * clamp20(gk_); hN_ = gN_ - 0.05f * clamp20(gN_); } \
    else     { hk_ = clamp20(gk_);               hN_ = clamp20(gN_); } \
    const bool kz_ = ((b) == 0) && (ta == 0); \
    const float Xk_ = (kz_ ? TWOC0 : CNF) * hk_; \
    const float XN_ = kz_ ? 0.f : CNF * hN_; \
    const float cc_ = c0a * (CRL##b) - s0a * (SRL##b); \
    const float ss_ = s0a * (CRL##b) + c0a * (SRL##b); \
    vo = make_float2(0.5f * (Xk_ * cc_ + XN_ * ss_), 0.5f * (Xk_ * ss_ - XN_ * cc_)); }

#define HEADS0(finv) { \
    const bool fin = (finv); \
    cf v0, v1, v2, v3, v4, v5, v6, v7; \
    MKVB(0, v0) MKVB(1, v1) MKVB(2, v2) MKVB(3, v3) \
    MKVB(4, v4) MKVB(5, v5) MKVB(6, v6) MKVB(7, v7) \
    dft8r<1>(v0, v1, v2, v3, v4, v5, v6, v7); \
    TWCHAINF(cww, sww); STORE8(A0j); }

#define TAILJ(j) { \
    const int k_ = ta + 256 * (j); \
    const float cc_ = c0a * (CRL##j) - s0a * (SRL##j); \
    const float ss_ = s0a * (CRL##j) + c0a * (SRL##j); \
    const float Cv_ = v##j.x * cc_ + v##j.y * ss_; \
    const float u_ = ((((j) == 0) && (ta == 0)) ? C0F : CNF) * Cv_; \
    if (init) g[k_] = u_; \
    else { const float gk_ = g[k_]; g[k_] = gk_ + 0.05f * (u_ - clamp20(gk_)); } }

#define TAILT3(initv) { \
    const bool init = (initv); \
    LOAD8(A0j); TWCHAINB(cww, sww); dft8r<-1>(v0, v1, v2, v3, v4, v5, v6, v7); \
    TAILJ(0) TAILJ(1) TAILJ(2) TAILJ(3) TAILJ(4) TAILJ(5) TAILJ(6) TAILJ(7) }

// S3 + mask + T0, all in registers (one 16-pt quad, q = 0 or 1)
#define QUADMASK(q) { \
    const int pb_ = 8 * ta + 4 * (q); \
    const int a_ = SWZ(pb_); \
    float4 lo_ = *(const float4*)(&wk[a_]); \
    float4 hi_ = *(const float4*)(&wk[a_ + 2]); \
    cf u0 = make_float2(lo_.x, lo_.y), u1 = make_float2(lo_.z, lo_.w); \
    cf u2 = make_float2(hi_.x, hi_.y), u3 = make_float2(hi_.z, hi_.w); \
    dft4r<1>(u0, u1, u2, u3); \
    u0 = make_float2(u0.x * (float)((mskv >> (4 * (q) + 0)) & 1u), 0.f); \
    u1 = make_float2(u1.x * (float)((mskv >> (4 * (q) + 1)) & 1u), 0.f); \
    u2 = make_float2(u2.x * (float)((mskv >> (4 * (q) + 2)) & 1u), 0.f); \
    u3 = make_float2(u3.x * (float)((mskv >> (4 * (q) + 3)) & 1u), 0.f); \
    dft4r<-1>(u0, u1, u2, u3); \
    *(float4*)(&wk[a_])     = make_float4(u0.x, u0.y, u1.x, u1.y); \
    *(float4*)(&wk[a_ + 2]) = make_float4(u2.x, u2.y, u3.x, u3.y); }

// Plain T0 quad (init path: input already masked & real)
#define QUADT0(q) { \
    const int pb_ = 8 * ta + 4 * (q); \
    const int a_ = SWZ(pb_); \
    float4 lo_ = *(const float4*)(&wk[a_]); \
    float4 hi_ = *(const float4*)(&wk[a_ + 2]); \
    cf u0 = make_float2(lo_.x, lo_.y), u1 = make_float2(lo_.z, lo_.w); \
    cf u2 = make_float2(hi_.x, hi_.y), u3 = make_float2(hi_.z, hi_.w); \
    dft4r<-1>(u0, u1, u2, u3); \
    *(float4*)(&wk[a_])     = make_float4(u0.x, u0.y, u1.x, u1.y); \
    *(float4*)(&wk[a_ + 2]) = make_float4(u2.x, u2.y, u3.x, u3.y); }

// Re-anchor every loop-carried invariant: empty asm "modifies" them, so LICM
// cannot hoist anything derived from them out of the enclosing loop, and the
// allocator never sees a giant invariant live set to spill (r2-r4 disease).
#define ANCHOR() asm volatile("" \
    : "+v"(cww), "+v"(sww), "+v"(coo), "+v"(soo), "+v"(cll), "+v"(sll), \
      "+v"(c0a), "+v"(s0a), "+v"(ta), "+v"(tswv), "+v"(s1bv), "+v"(t5v), \
      "+v"(s2kv), "+v"(s2cv), "+v"(mskv))

__global__ __launch_bounds__(256) void ista_fft_kernel(
    const float* __restrict__ x, const int* __restrict__ idxs,
    float* __restrict__ out)
{
    __shared__ __align__(16) cf wk[2048];   // 16 KB, swizzled slot space
    __shared__ float g[2048];               // 8 KB
    __shared__ unsigned mbm[64];

    const int t = threadIdx.x;
    int ta   = t;
    int t5v  = t >> 5;
    int s1bv = t & 31;
    int s2kv = t & 3;
    int s2cv = (t >> 2) & 7;
    int tswv = SWZ(t);

    if (t < 64) mbm[t] = 0u;
    __syncthreads();

    const int mi0 = load_idx(idxs, t), mi1 = load_idx(idxs, t + 256);
    const int yd0 = (mi0 & 1) ? (2047 - (mi0 >> 1)) : (mi0 >> 1);
    const int yd1 = (mi1 & 1) ? (2047 - (mi1 >> 1)) : (mi1 >> 1);
    const int pm0 = pinv(yd0), pm1 = pinv(yd1);
    atomicOr(&mbm[pm0 >> 5], 1u << (pm0 & 31));
    atomicOr(&mbm[pm1 >> 5], 1u << (pm1 & 31));
    const int sl0 = SWZ(pm0), sl1 = SWZ(pm1);
    __syncthreads();
    unsigned mskv = (mbm[t >> 2] >> ((t & 3) * 8)) & 0xffu;

    // the ONLY trig state: generators + half-angle pair (10 floats total)
    float s0a, c0a; sincosf(PIF * (float)t * (1.f / 4096.f), &s0a, &c0a);
    float sww, cww; sincosf(2.f * PIF * (float)t    * (1.f / 2048.f), &sww, &cww);
    float soo, coo; sincosf(2.f * PIF * (float)s1bv * (1.f / 256.f),  &soo, &coo);
    float sll, cll; sincosf(2.f * PIF * (float)s2kv * (1.f / 32.f),   &sll, &cll);

#pragma unroll 1
    for (int s = 0; s < SPW; ++s) {
        const int r = blockIdx.x * SPW + s;
        ANCHOR();

        // ---- init: wk = scatter(100*x[r, idxs]) in swizzled slot space ----
#pragma unroll
        for (int j = 0; j < 8; ++j) wk[t + 256 * j] = make_float2(0.f, 0.f);
        __syncthreads();
        wk[sl0] = make_float2(100.f * x[(size_t)r * 2048 + mi0], 0.f);
        wk[sl1] = make_float2(100.f * x[(size_t)r * 2048 + mi1], 0.f);
        __syncthreads();
        QUADT0(0) QUADT0(1)                    // plain T0
        __syncthreads();
        DITMID(A2j, cll, sll); __syncthreads();   // T1
        DITMID(A1j, coo, soo); __syncthreads();   // T2
        TAILT3(true);          __syncthreads();   // g = u0

        // ---- 99 iterations ----
#pragma unroll 1
        for (int it = 0; it < 99; ++it) {
            ANCHOR();
            HEADS0(false);         __syncthreads();   // S0 (reads g)
            DIFMID(A1j, coo, soo); __syncthreads();   // S1
            DIFMID(A2j, cll, sll); __syncthreads();   // S2
            QUADMASK(0) QUADMASK(1)                   // S3 + mask + T0 in regs
            __syncthreads();
            DITMID(A2j, cll, sll); __syncthreads();   // T1
            DITMID(A1j, coo, soo); __syncthreads();   // T2
            TAILT3(false);         __syncthreads();   // g update
        }

        // ---- final: out = 0.01 * IDCT(F') ----
        ANCHOR();
        HEADS0(true);          __syncthreads();
        DIFMID(A1j, coo, soo); __syncthreads();
        DIFMID(A2j, cll, sll); __syncthreads();
#pragma unroll
        for (int q = 0; q < 2; ++q) {          // S3 + reorder to x-order via g
            const int pb_ = 8 * ta + 4 * q;
            const int a_ = SWZ(pb_);
            float4 lo_ = *(const float4*)(&wk[a_]);
            float4 hi_ = *(const float4*)(&wk[a_ + 2]);
            cf u0 = make_float2(lo_.x, lo_.y), u1 = make_float2(lo_.z, lo_.w);
            cf u2 = make_float2(hi_.x, hi_.y), u3 = make_float2(hi_.z, hi_.w);
            dft4r<1>(u0, u1, u2, u3);
            {
                const int m = permf(pb_ + 0);
                g[(m < 1024) ? (m << 1) : (4095 - (m << 1))] = 0.01f * u0.x;
            }
            {
                const int m = permf(pb_ + 1);
                g[(m < 1024) ? (m << 1) : (4095 - (m << 1))] = 0.01f * u1.x;
            }
            {
                const int m = permf(pb_ + 2);
                g[(m < 1024) ? (m << 1) : (4095 - (m << 1))] = 0.01f * u2.x;
            }
            {
                const int m = permf(pb_ + 3);
                g[(m < 1024) ? (m << 1) : (4095 - (m << 1))] = 0.01f * u3.x;
            }
        }
        __syncthreads();
#pragma unroll
        for (int j = 0; j < 8; ++j)
            out[(size_t)r * 2048 + t + 256 * j] = g[t + 256 * j];
        __syncthreads();
    }
}

extern "C" void kernel_launch(void* const* d_in, const int* in_sizes, int n_in,
                              void* d_out, int out_size, void* d_ws, size_t ws_size,
                              hipStream_t stream) {
    (void)in_sizes; (void)n_in; (void)out_size; (void)d_ws; (void)ws_size;
    const float* x = (const float*)d_in[0];
    const int* idxs = (const int*)d_in[1];
    ista_fft_kernel<<<dim3(3072 / SPW), dim3(256), 0, stream>>>(x, idxs, (float*)d_out);
}

// Round 7
// 1652.551 us; speedup vs baseline: 4.3907x; 1.5514x over previous
//
#include <hip/hip_runtime.h>
#include <math.h>

// ============================================================================
// Persistent FFT ISTA solver, radix-8, spill-proof, PAIR-PACKED edition.
//
// Math per signal (identical recurrence to r1..r6, all PASSED):
//   u_{t+1} = u_t - 0.05*(I-P)*clamp20(u_t),  u_0 = 100*DCT(scatter(x[idxs]))
//   P*h = DCT2(mask(IDCT(h))),  out = 0.01*IDCT(u_99 - 0.05*clamp20(u_99)).
//
// r6 -> r7 (2-for-1 real packing): both transforms are real<->complex, so a
// full complex FFT carries 2x redundancy. Signals are processed in PAIRS:
//   IDCT: V_pair = V_s + i*V_{s+1}; FFT+ gives y_s + i*y_{s+1} (linearity).
//     V-build keeps the single-signal form with P = X0k+X1N, Q = X0N-X1k.
//   mask: multiply complex by keep (masks both signals).
//   DCT2: Y = FFT-(w_s + i*w_{s+1}); split Y0 = (Y[k]+conj(Y[Nk]))/2,
//     Y1 = (Y[k]-conj(Y[Nk]))/2i;  C_s[k] = cc*ReYs + ss*ImYs; u = ck*C.
//     Exchange: each thread stores Y back to the SAME slots it loaded
//     (A0j partition) -> no extra hazard, 1 barrier + 8 partner reads.
// Per-signal FFT work / LDS traffic / barriers all ~halve.
//
// Kept from r6 (THE spill fix, verified FETCH 23GB -> 12MB): only 15 scalar
// loop-invariants, re-anchored per iteration with empty asm (defeats LICM
// hoisting); twiddle powers rebuilt per stage by chained cmul.
//
// FFT: 2048 = 8*8*8*4, 256 threads, 8 cf/thread.
//   Slot p = 256b' + 32c' + 4d' + e' holds Y[m], m = b' + 8c' + 64d' + 512e'.
//   LDS XOR-swizzle swz(p) = p ^ (((p>>5)&7)<<2), conflict-minimal stages.
// LDS: wk 16KB + gp (float2 per k: signals s,s+1) 16KB + mbm = 33KB.
// Grid 768 x 256: 2 pairs (4 signals) per block, 3 resident blocks/CU.
// ============================================================================

#define PIF 3.14159265358979323846f
#define C0F 0.022097086912079608f      // sqrt(1/2048)
#define TWOC0 0.044194173824159216f    // 2*sqrt(1/2048)
#define CNF 0.03125f                   // sqrt(2/2048)
#define PPB 2                          // pairs per block; grid = 1536/PPB = 768

typedef float2 cf;

__device__ __forceinline__ int load_idx(const int* p, int j) {
    return (p[1] == 0) ? p[2 * j] : p[j];   // int64 (lo,0) pairs or int32
}
__device__ __forceinline__ int pinv(int m) {   // frequency -> slot
    return ((m & 7) << 8) | (((m >> 3) & 7) << 5) | (((m >> 6) & 7) << 2) | ((m >> 9) & 3);
}
__device__ __forceinline__ int permf(int p) {  // slot -> frequency
    return (p >> 8) | (((p >> 5) & 7) << 3) | (((p >> 2) & 7) << 6) | ((p & 3) << 9);
}
__device__ __forceinline__ float clamp20(float g) {
    return fminf(fmaxf(20.f * g, -1.f), 1.f);
}
__device__ __forceinline__ cf cadd(cf a, cf b) { return make_float2(a.x + b.x, a.y + b.y); }
__device__ __forceinline__ cf csub(cf a, cf b) { return make_float2(a.x - b.x, a.y - b.y); }
__device__ __forceinline__ cf cmul(cf a, cf b) {
    return make_float2(a.x * b.x - a.y * b.y, a.x * b.y + a.y * b.x);
}
__device__ __forceinline__ cf cmulc(cf a, cf b) {   // a * conj(b)
    return make_float2(a.x * b.x + a.y * b.y, a.y * b.x - a.x * b.y);
}
template <int S> __device__ __forceinline__ cf imul(cf z) {  // (S*i)*z
    return (S > 0) ? make_float2(-z.y, z.x) : make_float2(z.y, -z.x);
}

template <int S>
__device__ __forceinline__ void dft8r(cf& v0, cf& v1, cf& v2, cf& v3,
                                      cf& v4, cf& v5, cf& v6, cf& v7) {
    const float R2 = 0.70710678118654752f;
    cf A0 = cadd(v0, v4), D0 = csub(v0, v4);
    cf A1 = cadd(v1, v5), D1 = csub(v1, v5);
    cf A2 = cadd(v2, v6), D2 = csub(v2, v6);
    cf A3 = cadd(v3, v7), D3 = csub(v3, v7);
    const cf w8  = make_float2(R2, (S > 0) ? R2 : -R2);
    const cf w83 = make_float2(-R2, (S > 0) ? R2 : -R2);
    D1 = cmul(D1, w8);
    D2 = imul<S>(D2);
    D3 = cmul(D3, w83);
    cf E0 = cadd(A0, A2), E1 = csub(A0, A2);
    cf O0 = cadd(A1, A3), O1 = imul<S>(csub(A1, A3));
    cf F0 = cadd(D0, D2), F1 = csub(D0, D2);
    cf P0 = cadd(D1, D3), P1 = imul<S>(csub(D1, D3));
    v0 = cadd(E0, O0); v2 = cadd(E1, O1);
    v4 = csub(E0, O0); v6 = csub(E1, O1);
    v1 = cadd(F0, P0); v3 = cadd(F1, P1);
    v5 = csub(F0, P0); v7 = csub(F1, P1);
}

template <int S>
__device__ __forceinline__ void dft4r(cf& v0, cf& v1, cf& v2, cf& v3) {
    cf E0 = cadd(v0, v2), E1 = csub(v0, v2);
    cf O0 = cadd(v1, v3), O1 = imul<S>(csub(v1, v3));
    v0 = cadd(E0, O0); v1 = cadd(E1, O1);
    v2 = csub(E0, O0); v3 = csub(E1, O1);
}

// cos/sin(pi*b/16) literals, b = 0..7
#define CRL0 1.0f
#define CRL1 0.980785280403230449f
#define CRL2 0.923879532511286756f
#define CRL3 0.831469612302545237f
#define CRL4 0.707106781186547524f
#define CRL5 0.555570233019602225f
#define CRL6 0.382683432365089772f
#define CRL7 0.195090322016128268f
#define SRL0 0.0f
#define SRL1 CRL7
#define SRL2 CRL6
#define SRL3 CRL5
#define SRL4 CRL4
#define SRL5 CRL3
#define SRL6 CRL2
#define SRL7 CRL1

#define SWZ(p) ((p) ^ ((((p) >> 5) & 7) << 2))
#define A0j(j) (tswv + 256 * (j))
#define A1j(j) ((s1bv ^ ((j) << 2)) + 32 * (j) + 256 * t5v)
#define A2j(j) (s2kv + 4 * ((j) ^ s2cv) + 32 * s2cv + 256 * t5v)

#define LOAD8(A) cf v0 = wk[A(0)], v1 = wk[A(1)], v2 = wk[A(2)], v3 = wk[A(3)], \
                    v4 = wk[A(4)], v5 = wk[A(5)], v6 = wk[A(6)], v7 = wk[A(7)]
#define STORE8(A) wk[A(0)] = v0; wk[A(1)] = v1; wk[A(2)] = v2; wk[A(3)] = v3; \
                  wk[A(4)] = v4; wk[A(5)] = v5; wk[A(6)] = v6; wk[A(7)] = v7

// chained twiddle powers from the generator (PX,PY): w walks P^1..P^7
#define TWCHAINF(PX, PY) { const cf P_ = make_float2((PX), (PY)); cf w_ = P_; \
    v1 = cmul(v1, w_); w_ = cmul(w_, P_); v2 = cmul(v2, w_); w_ = cmul(w_, P_); \
    v3 = cmul(v3, w_); w_ = cmul(w_, P_); v4 = cmul(v4, w_); w_ = cmul(w_, P_); \
    v5 = cmul(v5, w_); w_ = cmul(w_, P_); v6 = cmul(v6, w_); w_ = cmul(w_, P_); \
    v7 = cmul(v7, w_); }
#define TWCHAINB(PX, PY) { const cf P_ = make_float2((PX), (PY)); cf w_ = P_; \
    v1 = cmulc(v1, w_); w_ = cmul(w_, P_); v2 = cmulc(v2, w_); w_ = cmul(w_, P_); \
    v3 = cmulc(v3, w_); w_ = cmul(w_, P_); v4 = cmulc(v4, w_); w_ = cmul(w_, P_); \
    v5 = cmulc(v5, w_); w_ = cmul(w_, P_); v6 = cmulc(v6, w_); w_ = cmul(w_, P_); \
    v7 = cmulc(v7, w_); }

#define DIFMID(A, PX, PY) { LOAD8(A); dft8r<1>(v0, v1, v2, v3, v4, v5, v6, v7); \
                            TWCHAINF(PX, PY); STORE8(A); }
#define DITMID(A, PX, PY) { LOAD8(A); TWCHAINB(PX, PY); \
                            dft8r<-1>(v0, v1, v2, v3, v4, v5, v6, v7); STORE8(A); }

// Packed V-build: V_pair[k] = V_s[k] + i*V_{s+1}[k] reduces to the single-
// signal form with P = X0k + X1N, Q = X0N - X1k (verified incl. k=0).
#define MKVBP(b, vo) { \
    const int k_ = ta + 256 * (b); \
    const int kN_ = (2048 - k_) & 2047; \
    const cf ga_ = gp[k_], gN_ = gp[kN_]; \
    float h0k_, h0N_, h1k_, h1N_; \
    if (fin) { h0k_ = ga_.x - 0.05f * clamp20(ga_.x); h0N_ = gN_.x - 0.05f * clamp20(gN_.x); \
               h1k_ = ga_.y - 0.05f * clamp20(ga_.y); h1N_ = gN_.y - 0.05f * clamp20(gN_.y); } \
    else     { h0k_ = clamp20(ga_.x); h0N_ = clamp20(gN_.x); \
               h1k_ = clamp20(ga_.y); h1N_ = clamp20(gN_.y); } \
    const bool kz_ = ((b) == 0) && (ta == 0); \
    const float s_ = kz_ ? TWOC0 : CNF; \
    const float X0k_ = s_ * h0k_, X1k_ = s_ * h1k_; \
    const float X0N_ = kz_ ? 0.f : CNF * h0N_; \
    const float X1N_ = kz_ ? 0.f : CNF * h1N_; \
    const float Pp_ = X0k_ + X1N_, Qq_ = X0N_ - X1k_; \
    const float cc_ = c0a * (CRL##b) - s0a * (SRL##b); \
    const float ss_ = s0a * (CRL##b) + c0a * (SRL##b); \
    vo = make_float2(0.5f * (Pp_ * cc_ + Qq_ * ss_), 0.5f * (Pp_ * ss_ - Qq_ * cc_)); }

#define HEADP(finv) { \
    const bool fin = (finv); \
    cf v0, v1, v2, v3, v4, v5, v6, v7; \
    MKVBP(0, v0) MKVBP(1, v1) MKVBP(2, v2) MKVBP(3, v3) \
    MKVBP(4, v4) MKVBP(5, v5) MKVBP(6, v6) MKVBP(7, v7) \
    dft8r<1>(v0, v1, v2, v3, v4, v5, v6, v7); \
    TWCHAINF(cww, sww); STORE8(A0j); }

// Tail per-k: split packed spectrum via conj-symmetry, DCT-II epilogue,
// update both signals. partner Y[Nk] read from wk (stored pre-barrier).
#define TPJ(j) { \
    const int k_ = ta + 256 * (j); \
    const int kp_ = (2048 - k_) & 2047; \
    const cf pz_ = wk[SWZ(kp_)]; \
    const float cc_ = c0a * (CRL##j) - s0a * (SRL##j); \
    const float ss_ = s0a * (CRL##j) + c0a * (SRL##j); \
    const float C0_ = 0.5f * (cc_ * (v##j.x + pz_.x) + ss_ * (v##j.y - pz_.y)); \
    const float C1_ = 0.5f * (cc_ * (v##j.y + pz_.y) + ss_ * (pz_.x - v##j.x)); \
    const float ck_ = ((((j) == 0) && (ta == 0)) ? C0F : CNF); \
    const float u0_ = ck_ * C0_, u1_ = ck_ * C1_; \
    if (init) { gp[k_] = make_float2(u0_, u1_); } \
    else { const cf go_ = gp[k_]; \
           gp[k_] = make_float2(go_.x + 0.05f * (u0_ - clamp20(go_.x)), \
                                go_.y + 0.05f * (u1_ - clamp20(go_.y))); } }

#define TAILP(initv) { \
    const bool init = (initv); \
    LOAD8(A0j); TWCHAINB(cww, sww); dft8r<-1>(v0, v1, v2, v3, v4, v5, v6, v7); \
    STORE8(A0j); \
    __syncthreads(); \
    TPJ(0) TPJ(1) TPJ(2) TPJ(3) TPJ(4) TPJ(5) TPJ(6) TPJ(7) }

// S3 + mask + T0 in registers; mask multiplies BOTH components (packed pair)
#define QUADMASK(q) { \
    const int pb_ = 8 * ta + 4 * (q); \
    const int a_ = SWZ(pb_); \
    float4 lo_ = *(const float4*)(&wk[a_]); \
    float4 hi_ = *(const float4*)(&wk[a_ + 2]); \
    cf u0 = make_float2(lo_.x, lo_.y), u1 = make_float2(lo_.z, lo_.w); \
    cf u2 = make_float2(hi_.x, hi_.y), u3 = make_float2(hi_.z, hi_.w); \
    dft4r<1>(u0, u1, u2, u3); \
    { const float k0_ = (float)((mskv >> (4 * (q) + 0)) & 1u); u0.x *= k0_; u0.y *= k0_; } \
    { const float k1_ = (float)((mskv >> (4 * (q) + 1)) & 1u); u1.x *= k1_; u1.y *= k1_; } \
    { const float k2_ = (float)((mskv >> (4 * (q) + 2)) & 1u); u2.x *= k2_; u2.y *= k2_; } \
    { const float k3_ = (float)((mskv >> (4 * (q) + 3)) & 1u); u3.x *= k3_; u3.y *= k3_; } \
    dft4r<-1>(u0, u1, u2, u3); \
    *(float4*)(&wk[a_])     = make_float4(u0.x, u0.y, u1.x, u1.y); \
    *(float4*)(&wk[a_ + 2]) = make_float4(u2.x, u2.y, u3.x, u3.y); }

#define QUADT0(q) { \
    const int pb_ = 8 * ta + 4 * (q); \
    const int a_ = SWZ(pb_); \
    float4 lo_ = *(const float4*)(&wk[a_]); \
    float4 hi_ = *(const float4*)(&wk[a_ + 2]); \
    cf u0 = make_float2(lo_.x, lo_.y), u1 = make_float2(lo_.z, lo_.w); \
    cf u2 = make_float2(hi_.x, hi_.y), u3 = make_float2(hi_.z, hi_.w); \
    dft4r<-1>(u0, u1, u2, u3); \
    *(float4*)(&wk[a_])     = make_float4(u0.x, u0.y, u1.x, u1.y); \
    *(float4*)(&wk[a_ + 2]) = make_float4(u2.x, u2.y, u3.x, u3.y); }

// THE r6-verified spill fix: re-anchor the 15 scalar invariants so LICM can't
// hoist derived values (FETCH 23GB -> 12MB when applied). Do not remove.
#define ANCHOR() asm volatile("" \
    : "+v"(cww), "+v"(sww), "+v"(coo), "+v"(soo), "+v"(cll), "+v"(sll), \
      "+v"(c0a), "+v"(s0a), "+v"(ta), "+v"(tswv), "+v"(s1bv), "+v"(t5v), \
      "+v"(s2kv), "+v"(s2cv), "+v"(mskv))

__global__ __launch_bounds__(256) void ista_fft_kernel(
    const float* __restrict__ x, const int* __restrict__ idxs,
    float* __restrict__ out)
{
    __shared__ __align__(16) cf wk[2048];   // 16 KB, swizzled slot space
    __shared__ __align__(16) cf gp[2048];   // 16 KB: gp[k] = (u_s[k], u_{s+1}[k])
    __shared__ unsigned mbm[64];

    const int t = threadIdx.x;
    int ta   = t;
    int t5v  = t >> 5;
    int s1bv = t & 31;
    int s2kv = t & 3;
    int s2cv = (t >> 2) & 7;
    int tswv = SWZ(t);

    if (t < 64) mbm[t] = 0u;
    __syncthreads();

    const int mi0 = load_idx(idxs, t), mi1 = load_idx(idxs, t + 256);
    const int yd0 = (mi0 & 1) ? (2047 - (mi0 >> 1)) : (mi0 >> 1);
    const int yd1 = (mi1 & 1) ? (2047 - (mi1 >> 1)) : (mi1 >> 1);
    const int pm0 = pinv(yd0), pm1 = pinv(yd1);
    atomicOr(&mbm[pm0 >> 5], 1u << (pm0 & 31));
    atomicOr(&mbm[pm1 >> 5], 1u << (pm1 & 31));
    const int sl0 = SWZ(pm0), sl1 = SWZ(pm1);
    __syncthreads();
    unsigned mskv = (mbm[t >> 2] >> ((t & 3) * 8)) & 0xffu;

    // the ONLY trig state: generators + half-angle pair (8 floats)
    float s0a, c0a; sincosf(PIF * (float)t * (1.f / 4096.f), &s0a, &c0a);
    float sww, cww; sincosf(2.f * PIF * (float)t    * (1.f / 2048.f), &sww, &cww);
    float soo, coo; sincosf(2.f * PIF * (float)s1bv * (1.f / 256.f),  &soo, &coo);
    float sll, cll; sincosf(2.f * PIF * (float)s2kv * (1.f / 32.f),   &sll, &cll);

#pragma unroll 1
    for (int s = 0; s < PPB; ++s) {
        const int pi = blockIdx.x * PPB + s;      // pair index
        const int r0 = 2 * pi, r1 = r0 + 1;
        ANCHOR();

        // ---- init: wk = scatter(100*(x0 + i*x1)) in swizzled slot space ----
#pragma unroll
        for (int j = 0; j < 8; ++j) wk[t + 256 * j] = make_float2(0.f, 0.f);
        __syncthreads();
        wk[sl0] = make_float2(100.f * x[(size_t)r0 * 2048 + mi0],
                              100.f * x[(size_t)r1 * 2048 + mi0]);
        wk[sl1] = make_float2(100.f * x[(size_t)r0 * 2048 + mi1],
                              100.f * x[(size_t)r1 * 2048 + mi1]);
        __syncthreads();
        QUADT0(0) QUADT0(1)                       // plain T0 (input pre-masked)
        __syncthreads();
        DITMID(A2j, cll, sll); __syncthreads();   // T1
        DITMID(A1j, coo, soo); __syncthreads();   // T2
        TAILP(true);           __syncthreads();   // gp = (u0_s, u0_{s+1})

        // ---- 99 iterations (per PAIR) ----
#pragma unroll 1
        for (int it = 0; it < 99; ++it) {
            ANCHOR();
            HEADP(false);          __syncthreads();   // S0 (reads gp)
            DIFMID(A1j, coo, soo); __syncthreads();   // S1
            DIFMID(A2j, cll, sll); __syncthreads();   // S2
            QUADMASK(0) QUADMASK(1)                   // S3 + mask + T0 in regs
            __syncthreads();
            DITMID(A2j, cll, sll); __syncthreads();   // T1
            DITMID(A1j, coo, soo); __syncthreads();   // T2
            TAILP(false);          __syncthreads();   // split + gp update
        }

        // ---- final: out_s = 0.01*Re, out_{s+1} = 0.01*Im of IDCT(F') ----
        ANCHOR();
        HEADP(true);           __syncthreads();
        DIFMID(A1j, coo, soo); __syncthreads();
        DIFMID(A2j, cll, sll); __syncthreads();
#pragma unroll
        for (int q = 0; q < 2; ++q) {          // S3 + reorder to x-order via gp
            const int pb_ = 8 * ta + 4 * q;
            const int a_ = SWZ(pb_);
            float4 lo_ = *(const float4*)(&wk[a_]);
            float4 hi_ = *(const float4*)(&wk[a_ + 2]);
            cf u0 = make_float2(lo_.x, lo_.y), u1 = make_float2(lo_.z, lo_.w);
            cf u2 = make_float2(hi_.x, hi_.y), u3 = make_float2(hi_.z, hi_.w);
            dft4r<1>(u0, u1, u2, u3);
            {
                const int m = permf(pb_ + 0);
                gp[(m < 1024) ? (m << 1) : (4095 - (m << 1))] =
                    make_float2(0.01f * u0.x, 0.01f * u0.y);
            }
            {
                const int m = permf(pb_ + 1);
                gp[(m < 1024) ? (m << 1) : (4095 - (m << 1))] =
                    make_float2(0.01f * u1.x, 0.01f * u1.y);
            }
            {
                const int m = permf(pb_ + 2);
                gp[(m < 1024) ? (m << 1) : (4095 - (m << 1))] =
                    make_float2(0.01f * u2.x, 0.01f * u2.y);
            }
            {
                const int m = permf(pb_ + 3);
                gp[(m < 1024) ? (m << 1) : (4095 - (m << 1))] =
                    make_float2(0.01f * u3.x, 0.01f * u3.y);
            }
        }
        __syncthreads();
#pragma unroll
        for (int j = 0; j < 8; ++j) {
            const cf o_ = gp[t + 256 * j];
            out[(size_t)r0 * 2048 + t + 256 * j] = o_.x;
            out[(size_t)r1 * 2048 + t + 256 * j] = o_.y;
        }
        __syncthreads();
    }
}

extern "C" void kernel_launch(void* const* d_in, const int* in_sizes, int n_in,
                              void* d_out, int out_size, void* d_ws, size_t ws_size,
                              hipStream_t stream) {
    (void)in_sizes; (void)n_in; (void)out_size; (void)d_ws; (void)ws_size;
    const float* x = (const float*)d_in[0];
    const int* idxs = (const int*)d_in[1];
    // 3072 signals = 1536 pairs; PPB pairs per block
    ista_fft_kernel<<<dim3(1536 / PPB), dim3(256), 0, stream>>>(x, idxs, (float*)d_out);
}